// Round 1
// baseline (81.154 us; speedup 1.0000x reference)
//
#include <hip/hip_runtime.h>
#include <math.h>

#define HH 480
#define WW 640
#define NL 100
#define NREF 20
#define RPB 2                 /* rows per block */
#define NB (HH / RPB)         /* 240 blocks */

// ws layout: partial[col][block], col = t*4+q (80 cols), col stride NB floats
// (960 B), then one int ticket at float index NREF*4*NB (byte 76800).
// SINGLE-DISPATCH fusion: partials are written with agent-scope (sc1) relaxed
// scoped stores that BYPASS the non-coherent per-XCD L2s and land at the
// device coherence point; a wave-wide s_waitcnt vmcnt(0) (completion wait, NOT
// a threadfence -- R7 showed fence-driven L2 writeback costs ~50 us) orders
// them before the device-scope ticket bump. Last-arriving block (elected via
// ticket % NB == NB-1, robust to arbitrary poison garbage in the ticket word,
// so NO zeroing pass is needed) re-reads the partials with agent-scope loads
// and reproduces the old finalize's exact pairwise summation order ->
// bitwise-identical result (absmax stays 0.0).
// RPB=2 beats RPB=1 (R6 79.1 vs R8 82.2): half the halo staging, half the
// rank-loop instances, half the partial matrix.

__global__ __launch_bounds__(256) void plane_fused_kernel(
    const float* __restrict__ depth, const int* __restrict__ valid,
    const float* __restrict__ line_pred, const float* __restrict__ line_score,
    float* __restrict__ w, float* __restrict__ out) {
    __shared__ float ds[(RPB + 2) * WW];   // rows base-1 .. base+RPB (zero-filled OOB)
    __shared__ int vsh[RPB * WW];
    __shared__ float s_sc[NL];
    __shared__ float s_vert[NREF][6];      // vx,vy x 3 per rank
    __shared__ float s_ae[RPB][NREF * 3];  // per-row edge constant
    __shared__ float s_ey[NREF * 3];
    __shared__ float s_col[NREF * 4];      // finalize: per-rank column sums
    __shared__ int s_cnt[2];               // finalize: ballot counts
    __shared__ int s_last;                 // election flag (block-uniform)

    const int tid = threadIdx.x;
    const int base = blockIdx.x * RPB;

    if (tid < NL) s_sc[tid] = ((const float2*)line_score)[tid].x;

    // stage depth: (RPB+2) rows x 160 float4
    for (int idx = tid; idx < (RPB + 2) * (WW / 4); idx += 256) {
        const int lr = idx / (WW / 4);
        const int c4 = idx - lr * (WW / 4);
        const int g = base - 1 + lr;
        float4 v = make_float4(0.f, 0.f, 0.f, 0.f);
        if ((unsigned)g < (unsigned)HH) v = ((const float4*)depth)[g * (WW / 4) + c4];
        ((float4*)ds)[idx] = v;
    }
    // stage valid rows
    for (int idx = tid; idx < RPB * (WW / 4); idx += 256)
        ((int4*)vsh)[idx] = ((const int4*)valid)[base * (WW / 4) + idx];
    __syncthreads();

    // stable rank == jax.lax.top_k order (desc, ties -> lower idx); permutation
    if (tid < NL) {
        const float s0 = s_sc[tid];
        int rank = 0;
        for (int j = 0; j < NL; j++) {
            const float sj = s_sc[j];
            rank += ((sj > s0) || (sj == s0 && j < tid)) ? 1 : 0;
        }
        if (rank < NREF) {
            const float2 c01 = ((const float2*)line_pred)[3 * tid];
            const float2 c23 = ((const float2*)line_pred)[3 * tid + 1];
            const float2 c45 = ((const float2*)line_pred)[3 * tid + 2];
            // round half-even == jnp.round; clip to image
            s_vert[rank][0] = fminf(fmaxf(rintf(c01.x * (float)WW), 0.f), (float)(WW - 1));
            s_vert[rank][1] = fminf(fmaxf(rintf(c01.y * (float)HH), 0.f), (float)(HH - 1));
            s_vert[rank][2] = fminf(fmaxf(rintf(c23.x * (float)WW), 0.f), (float)(WW - 1));
            s_vert[rank][3] = fminf(fmaxf(rintf(c23.y * (float)HH), 0.f), (float)(HH - 1));
            s_vert[rank][4] = fminf(fmaxf(rintf(c45.x * (float)WW), 0.f), (float)(WW - 1));
            s_vert[rank][5] = fminf(fmaxf(rintf(c45.y * (float)HH), 0.f), (float)(HH - 1));
        }
    }
    __syncthreads();

    // per-row edge constants: d_e(px) = ae_e - ey_e*px (exact: integer fp32
    // operands, |terms| < 2^22 -> sign test bitwise-identical to reference)
    if (tid < NREF * 3) {
        const int t = tid / 3, e = tid - 3 * t, n = (e + 1) % 3;
        const float vx = s_vert[t][2 * e], vy = s_vert[t][2 * e + 1];
        const float ex = s_vert[t][2 * n] - vx, eyv = s_vert[t][2 * n + 1] - vy;
        s_ey[tid] = eyv;
        #pragma unroll
        for (int rr = 0; rr < RPB; rr++)
            s_ae[rr][tid] = fmaf(ex, (float)(base + rr) - vy, eyv * vx);
    }
    __syncthreads();

    const int wid = tid >> 6, lane = tid & 63;
    float eyr[5][3];
    #pragma unroll
    for (int i = 0; i < 5; i++)
        #pragma unroll
        for (int e = 0; e < 3; e++)
            eyr[i][e] = s_ey[(wid * 5 + i) * 3 + e];

    float acc[5][4];
    #pragma unroll
    for (int i = 0; i < 5; i++)
        #pragma unroll
        for (int q = 0; q < 4; q++) acc[i][q] = 0.f;

    #pragma unroll
    for (int rr = 0; rr < RPB; rr++) {
        float ae[5][3];
        #pragma unroll
        for (int i = 0; i < 5; i++)
            #pragma unroll
            for (int e = 0; e < 3; e++)
                ae[i][e] = s_ae[rr][(wid * 5 + i) * 3 + e];
        const float* rm = ds + rr * WW;
        const float* rc = ds + (rr + 1) * WW;
        const float* rp = ds + (rr + 2) * WW;
        const int* vrow = vsh + rr * WW;
        #pragma unroll
        for (int j = 0; j < 10; j++) {
            const int x = j * 64 + lane;
            const float px = (float)x;
            const float fl = (x > 0) ? 1.f : 0.f;
            const float fr = (x < WW - 1) ? 1.f : 0.f;
            const int xm = x - (x > 0), xp = x + (x < WW - 1);
            const float a00 = rm[xm] * fl, a01 = rm[x], a02 = rm[xp] * fr;
            const float a10 = rc[xm] * fl,               a12 = rc[xp] * fr;
            const float a20 = rp[xm] * fl, a21 = rp[x], a22 = rp[xp] * fr;
            // XLA conv = cross-correlation, zero pad
            const float gx = (a00 - a02) + 2.f * (a10 - a12) + (a20 - a22);
            const float gy = (a00 + 2.f * a01 + a02) - (a20 + 2.f * a21 + a22);
            const float nx = -gx, ny = -gy;
            const float s2 = nx * nx + ny * ny;
            const bool vm = (vrow[x] != 0);
            #pragma unroll
            for (int i = 0; i < 5; i++) {
                const float d0 = fmaf(-eyr[i][0], px, ae[i][0]);
                const float d1 = fmaf(-eyr[i][1], px, ae[i][1]);
                const float d2 = fmaf(-eyr[i][2], px, ae[i][2]);
                const float dmin = fminf(fminf(d0, d1), d2);
                const float dmax = fmaxf(fmaxf(d0, d1), d2);
                const bool m = ((dmin >= 0.f) | (dmax <= 0.f)) & vm;
                const float mf = m ? 1.f : 0.f;
                acc[i][0] += mf;
                acc[i][1] = fmaf(mf, nx, acc[i][1]);
                acc[i][2] = fmaf(mf, ny, acc[i][2]);
                acc[i][3] = fmaf(mf, s2, acc[i][3]);
            }
        }
    }

    // wave-level reduction; waves own disjoint triangles -> no cross-wave step
    #pragma unroll
    for (int off = 32; off > 0; off >>= 1)
        #pragma unroll
        for (int i = 0; i < 5; i++)
            #pragma unroll
            for (int q = 0; q < 4; q++)
                acc[i][q] += __shfl_down(acc[i][q], off);

    // agent-scope (sc1) relaxed stores: bypass non-coherent per-XCD L2,
    // land at the device coherence point. col = (wid*5+i)*4+q, row = blockIdx.
    if (lane == 0) {
        #pragma unroll
        for (int i = 0; i < 5; i++)
            #pragma unroll
            for (int q = 0; q < 4; q++)
                __hip_atomic_store(
                    &w[((wid * 5 + i) * 4 + q) * NB + blockIdx.x], acc[i][q],
                    __ATOMIC_RELAXED, __HIP_MEMORY_SCOPE_AGENT);
    }
    // completion wait (NOT a fence): scoped stores acked at coherence point
    // before this wave can pass. Wave-uniform instruction.
    asm volatile("s_waitcnt vmcnt(0)" ::: "memory");
    __syncthreads();

    // ticket election: exactly one block in any 240 consecutive ticket values
    // sees t % NB == NB-1 -> robust to poison garbage, no zeroing needed.
    if (tid == 0) {
        int* ticket = (int*)(w + NREF * 4 * NB);
        const int t = __hip_atomic_fetch_add(ticket, 1, __ATOMIC_RELAXED,
                                             __HIP_MEMORY_SCOPE_AGENT);
        s_last = (((unsigned)t % (unsigned)NB) == (unsigned)(NB - 1)) ? 1 : 0;
    }
    __syncthreads();
    if (!s_last) return;

    // ---- finalize (elected block only; condition is block-uniform) ----
    // top_num = min(#(softmax prob0 > 0.6), 20); include-flag = (rank < top_num)
    int flag = 0;
    if (tid < NL) {
        const float2 sc = ((const float2*)line_score)[tid];
        const float p0 = 1.0f / (1.0f + expf(sc.y - sc.x));
        flag = (p0 > 0.6f) ? 1 : 0;
    }
    const unsigned long long b = __ballot(flag);
    if (lane == 0 && wid < 2) s_cnt[wid] = __popcll(b);

    // sum partial columns with agent-scope loads (read the coherence point,
    // not a possibly-stale L2). Summation order replicates the old finalize
    // kernel exactly (stride-4 partial sums, then (x+y)+(z+w)) -> bitwise
    // identical result.
    if (tid < NREF * 4) {
        float* colp = w + tid * NB;
        float sx0 = 0.f, sx1 = 0.f, sx2 = 0.f, sx3 = 0.f;
        #pragma unroll 4
        for (int p = 0; p < NB / 4; p++) {
            const unsigned long long u0 = __hip_atomic_load(
                (unsigned long long*)(colp + 4 * p),
                __ATOMIC_RELAXED, __HIP_MEMORY_SCOPE_AGENT);
            const unsigned long long u1 = __hip_atomic_load(
                (unsigned long long*)(colp + 4 * p + 2),
                __ATOMIC_RELAXED, __HIP_MEMORY_SCOPE_AGENT);
            sx0 += __uint_as_float((unsigned)u0);
            sx1 += __uint_as_float((unsigned)(u0 >> 32));
            sx2 += __uint_as_float((unsigned)u1);
            sx3 += __uint_as_float((unsigned)(u1 >> 32));
        }
        s_col[tid] = (sx0 + sx1) + (sx2 + sx3);
    }
    __syncthreads();

    const int topnum = min(s_cnt[0] + s_cnt[1], NREF);
    float val = 0.f, inc = 0.f;
    if (tid < NREF) {
        const float c  = s_col[tid * 4 + 0];
        const float sx = s_col[tid * 4 + 1];
        const float sy = s_col[tid * 4 + 2];
        const float sq = s_col[tid * 4 + 3];
        const float safe = fmaxf(c, 1.f);
        const float mx = sx / safe, my = sy / safe;
        // (var_x+var_y) expanded; exact 0 when c==0
        const float var = (sq - 2.f * mx * sx - 2.f * my * sy
                           + c * (mx * mx + my * my)) / safe;
        inc = ((c >= 100.f) && (tid < topnum)) ? 1.f : 0.f;
        val = inc * var;
    }
    if (tid < 64) { // lanes 20..63 carry zeros
        #pragma unroll
        for (int off = 32; off > 0; off >>= 1) {
            val += __shfl_down(val, off);
            inc += __shfl_down(inc, off);
        }
        if (tid == 0) out[0] = val / fmaxf(inc, 1.f);
    }
}

extern "C" void kernel_launch(void* const* d_in, const int* in_sizes, int n_in,
                              void* d_out, int out_size, void* d_ws, size_t ws_size,
                              hipStream_t stream) {
    const float* depth_pred = (const float*)d_in[0];
    // d_in[1] = depth_gt (unused by reference)
    const float* line_pred  = (const float*)d_in[2];
    const float* line_score = (const float*)d_in[3];
    const int*   valid_mask = (const int*)d_in[4];
    float* out = (float*)d_out;
    float* w = (float*)d_ws;

    plane_fused_kernel<<<NB, 256, 0, stream>>>(depth_pred, valid_mask,
                                               line_pred, line_score, w, out);
}

// Round 2
// 76.988 us; speedup vs baseline: 1.0541x; 1.0541x over previous
//
#include <hip/hip_runtime.h>
#include <math.h>

#define HH 480
#define WW 640
#define NL 100
#define NREF 20
#define RPB 2                 /* rows per block */
#define NB (HH / RPB)         /* 240 blocks */

// ws layout: PART only. partial[col][block], col = t*4+q (80 cols),
// col stride NB floats (960 B, 16B-aligned). ~76.8 KB. No zeroing needed:
// every entry is plain-stored by its owning block. NO atomics, NO fences —
// the kernel boundary (stream order) provides cross-XCD coherence for free.
// R7: explicit __threadfence costs ~50 µs (L2 writeback storms).
// R9 (this session): single-dispatch fusion with sc1 scoped stores + ticket
// election REGRESSED 78.2→81.2 — the elected block's uncached agent-scope
// column re-read (~6 µs serialized at the tail) outweighs the ~3 µs
// dispatch+drain saving. Two dependent dispatches is the right structure.
// RPB=2 beats RPB=1 (R6 79.1 vs R8 82.2): half the halo staging, half the
// rank-loop instances, half the partial matrix.
// valid_mask is NOT staged to LDS: read exactly once per element, zero reuse
// — direct coalesced global loads hoist under the triangle-test VALU work.

__global__ __launch_bounds__(256) void plane_main_kernel(
    const float* __restrict__ depth, const int* __restrict__ valid,
    const float* __restrict__ line_pred, const float* __restrict__ line_score,
    float* __restrict__ w) {
    __shared__ float ds[(RPB + 2) * WW];   // rows base-1 .. base+RPB (zero-filled OOB)
    __shared__ float s_sc[NL];
    __shared__ float s_vert[NREF][6];      // vx,vy x 3 per rank
    __shared__ float s_ae[RPB][NREF * 3];  // per-row edge constant
    __shared__ float s_ey[NREF * 3];

    const int tid = threadIdx.x;
    const int base = blockIdx.x * RPB;

    if (tid < NL) s_sc[tid] = ((const float2*)line_score)[tid].x;

    // stage depth: (RPB+2) rows x 160 float4
    for (int idx = tid; idx < (RPB + 2) * (WW / 4); idx += 256) {
        const int lr = idx / (WW / 4);
        const int c4 = idx - lr * (WW / 4);
        const int g = base - 1 + lr;
        float4 v = make_float4(0.f, 0.f, 0.f, 0.f);
        if ((unsigned)g < (unsigned)HH) v = ((const float4*)depth)[g * (WW / 4) + c4];
        ((float4*)ds)[idx] = v;
    }
    __syncthreads();

    // stable rank == jax.lax.top_k order (desc, ties -> lower idx); permutation
    if (tid < NL) {
        const float s0 = s_sc[tid];
        int rank = 0;
        for (int j = 0; j < NL; j++) {
            const float sj = s_sc[j];
            rank += ((sj > s0) || (sj == s0 && j < tid)) ? 1 : 0;
        }
        if (rank < NREF) {
            const float2 c01 = ((const float2*)line_pred)[3 * tid];
            const float2 c23 = ((const float2*)line_pred)[3 * tid + 1];
            const float2 c45 = ((const float2*)line_pred)[3 * tid + 2];
            // round half-even == jnp.round; clip to image
            s_vert[rank][0] = fminf(fmaxf(rintf(c01.x * (float)WW), 0.f), (float)(WW - 1));
            s_vert[rank][1] = fminf(fmaxf(rintf(c01.y * (float)HH), 0.f), (float)(HH - 1));
            s_vert[rank][2] = fminf(fmaxf(rintf(c23.x * (float)WW), 0.f), (float)(WW - 1));
            s_vert[rank][3] = fminf(fmaxf(rintf(c23.y * (float)HH), 0.f), (float)(HH - 1));
            s_vert[rank][4] = fminf(fmaxf(rintf(c45.x * (float)WW), 0.f), (float)(WW - 1));
            s_vert[rank][5] = fminf(fmaxf(rintf(c45.y * (float)HH), 0.f), (float)(HH - 1));
        }
    }
    __syncthreads();

    // per-row edge constants: d_e(px) = ae_e - ey_e*px (exact: integer fp32
    // operands, |terms| < 2^22 -> sign test bitwise-identical to reference)
    if (tid < NREF * 3) {
        const int t = tid / 3, e = tid - 3 * t, n = (e + 1) % 3;
        const float vx = s_vert[t][2 * e], vy = s_vert[t][2 * e + 1];
        const float ex = s_vert[t][2 * n] - vx, eyv = s_vert[t][2 * n + 1] - vy;
        s_ey[tid] = eyv;
        #pragma unroll
        for (int rr = 0; rr < RPB; rr++)
            s_ae[rr][tid] = fmaf(ex, (float)(base + rr) - vy, eyv * vx);
    }
    __syncthreads();

    const int wid = tid >> 6, lane = tid & 63;
    float eyr[5][3];
    #pragma unroll
    for (int i = 0; i < 5; i++)
        #pragma unroll
        for (int e = 0; e < 3; e++)
            eyr[i][e] = s_ey[(wid * 5 + i) * 3 + e];

    float acc[5][4];
    #pragma unroll
    for (int i = 0; i < 5; i++)
        #pragma unroll
        for (int q = 0; q < 4; q++) acc[i][q] = 0.f;

    #pragma unroll
    for (int rr = 0; rr < RPB; rr++) {
        float ae[5][3];
        #pragma unroll
        for (int i = 0; i < 5; i++)
            #pragma unroll
            for (int e = 0; e < 3; e++)
                ae[i][e] = s_ae[rr][(wid * 5 + i) * 3 + e];
        const float* rm = ds + rr * WW;
        const float* rc = ds + (rr + 1) * WW;
        const float* rp = ds + (rr + 2) * WW;
        const int* vrow = valid + (base + rr) * WW;  // direct global, coalesced
        #pragma unroll
        for (int j = 0; j < 10; j++) {
            const int x = j * 64 + lane;
            const float px = (float)x;
            const float fl = (x > 0) ? 1.f : 0.f;
            const float fr = (x < WW - 1) ? 1.f : 0.f;
            const int xm = x - (x > 0), xp = x + (x < WW - 1);
            const float a00 = rm[xm] * fl, a01 = rm[x], a02 = rm[xp] * fr;
            const float a10 = rc[xm] * fl,               a12 = rc[xp] * fr;
            const float a20 = rp[xm] * fl, a21 = rp[x], a22 = rp[xp] * fr;
            // XLA conv = cross-correlation, zero pad
            const float gx = (a00 - a02) + 2.f * (a10 - a12) + (a20 - a22);
            const float gy = (a00 + 2.f * a01 + a02) - (a20 + 2.f * a21 + a22);
            const float nx = -gx, ny = -gy;
            const float s2 = nx * nx + ny * ny;
            const bool vm = (vrow[x] != 0);
            #pragma unroll
            for (int i = 0; i < 5; i++) {
                const float d0 = fmaf(-eyr[i][0], px, ae[i][0]);
                const float d1 = fmaf(-eyr[i][1], px, ae[i][1]);
                const float d2 = fmaf(-eyr[i][2], px, ae[i][2]);
                const float dmin = fminf(fminf(d0, d1), d2);
                const float dmax = fmaxf(fmaxf(d0, d1), d2);
                const bool m = ((dmin >= 0.f) | (dmax <= 0.f)) & vm;
                const float mf = m ? 1.f : 0.f;
                acc[i][0] += mf;
                acc[i][1] = fmaf(mf, nx, acc[i][1]);
                acc[i][2] = fmaf(mf, ny, acc[i][2]);
                acc[i][3] = fmaf(mf, s2, acc[i][3]);
            }
        }
    }

    // wave-level reduction; waves own disjoint triangles -> no cross-wave step
    #pragma unroll
    for (int off = 32; off > 0; off >>= 1)
        #pragma unroll
        for (int i = 0; i < 5; i++)
            #pragma unroll
            for (int q = 0; q < 4; q++)
                acc[i][q] += __shfl_down(acc[i][q], off);
    if (lane == 0) {
        // plain stores, zero contention: col = (wid*5+i)*4+q, row = blockIdx.x
        #pragma unroll
        for (int i = 0; i < 5; i++)
            #pragma unroll
            for (int q = 0; q < 4; q++)
                w[((wid * 5 + i) * 4 + q) * NB + blockIdx.x] = acc[i][q];
    }
}

__global__ __launch_bounds__(128) void plane_finalize_kernel(
    const float* __restrict__ line_score, const float* __restrict__ w,
    float* __restrict__ out) {
    __shared__ float s_col[NREF * 4];
    __shared__ int s_cnt[2];
    const int tid = threadIdx.x; // 0..127
    const int lane = tid & 63, wid = tid >> 6;

    // top_num = min(#(softmax prob0 > 0.6), 20); include-flag = (rank < top_num)
    int flag = 0;
    if (tid < NL) {
        const float2 sc = ((const float2*)line_score)[tid];
        const float p0 = 1.0f / (1.0f + expf(sc.y - sc.x));
        flag = (p0 > 0.6f) ? 1 : 0;
    }
    const unsigned long long b = __ballot(flag);
    if (lane == 0) s_cnt[wid] = __popcll(b);

    // sum partial columns (NB contiguous floats each, float4). unroll 12:
    // 12 independent float4 loads in flight -> 5 latency round trips not 15.
    // Accumulation order identical to unroll-4 version (same sequential adds)
    // -> bitwise-identical result.
    if (tid < NREF * 4) {
        const float4* col = (const float4*)(w + tid * NB);
        float4 s4 = make_float4(0.f, 0.f, 0.f, 0.f);
        #pragma unroll 12
        for (int p = 0; p < NB / 4; p++) {
            const float4 v = col[p];
            s4.x += v.x; s4.y += v.y; s4.z += v.z; s4.w += v.w;
        }
        s_col[tid] = (s4.x + s4.y) + (s4.z + s4.w);
    }
    __syncthreads();

    const int topnum = min(s_cnt[0] + s_cnt[1], NREF);
    float val = 0.f, inc = 0.f;
    if (tid < NREF) {
        const float c  = s_col[tid * 4 + 0];
        const float sx = s_col[tid * 4 + 1];
        const float sy = s_col[tid * 4 + 2];
        const float sq = s_col[tid * 4 + 3];
        const float safe = fmaxf(c, 1.f);
        const float mx = sx / safe, my = sy / safe;
        // (var_x+var_y) expanded; exact 0 when c==0
        const float var = (sq - 2.f * mx * sx - 2.f * my * sy
                           + c * (mx * mx + my * my)) / safe;
        inc = ((c >= 100.f) && (tid < topnum)) ? 1.f : 0.f;
        val = inc * var;
    }
    if (tid < 64) { // lanes 20..63 carry zeros
        #pragma unroll
        for (int off = 32; off > 0; off >>= 1) {
            val += __shfl_down(val, off);
            inc += __shfl_down(inc, off);
        }
        if (tid == 0) out[0] = val / fmaxf(inc, 1.f);
    }
}

extern "C" void kernel_launch(void* const* d_in, const int* in_sizes, int n_in,
                              void* d_out, int out_size, void* d_ws, size_t ws_size,
                              hipStream_t stream) {
    const float* depth_pred = (const float*)d_in[0];
    // d_in[1] = depth_gt (unused by reference)
    const float* line_pred  = (const float*)d_in[2];
    const float* line_score = (const float*)d_in[3];
    const int*   valid_mask = (const int*)d_in[4];
    float* out = (float*)d_out;
    float* w = (float*)d_ws;

    plane_main_kernel<<<NB, 256, 0, stream>>>(depth_pred, valid_mask,
                                              line_pred, line_score, w);
    plane_finalize_kernel<<<1, 128, 0, stream>>>(line_score, w, out);
}

// Round 3
// 75.456 us; speedup vs baseline: 1.0755x; 1.0203x over previous
//
#include <hip/hip_runtime.h>
#include <math.h>

#define HH 480
#define WW 640
#define NL 100
#define NREF 20
#define RPB 2                 /* rows per block */
#define NB (HH / RPB)         /* 240 blocks */

// ws layout: PART only. partial[col][block], col = t*4+q (80 cols),
// col stride NB floats (960 B, 16B-aligned). ~76.8 KB. No zeroing needed:
// every entry is plain-stored by its owning block. NO atomics, NO fences —
// the kernel boundary (stream order) provides cross-XCD coherence for free.
// R7: explicit __threadfence costs ~50 µs (L2 writeback storms).
// R9: single-dispatch fusion (sc1 stores + ticket election) REGRESSED
// 78.2→81.2 — elected block's uncached agent-scope re-read (~6 µs tail)
// outweighs the ~3 µs dispatch+drain saving. Two dispatches is right.
// R10: valid de-staged (read-once, zero reuse) + finalize unroll: 77.0.
// R11 (this round): valid loads PRELOADED to registers before the prologue
// barriers — __syncthreads has full-fence semantics so the compiler cannot
// hoist global loads past it; preloading lets their ~900 cyc latency ride
// the barrier wait that already covers the depth staging loads.
// RPB=2 beats RPB=1 (R6 79.1 vs R8 82.2): half the halo staging, half the
// rank-loop instances, half the partial matrix.

__global__ __launch_bounds__(256) void plane_main_kernel(
    const float* __restrict__ depth, const int* __restrict__ valid,
    const float* __restrict__ line_pred, const float* __restrict__ line_score,
    float* __restrict__ w) {
    __shared__ float ds[(RPB + 2) * WW];   // rows base-1 .. base+RPB (zero-filled OOB)
    __shared__ float s_sc[NL];
    __shared__ float s_vert[NREF][6];      // vx,vy x 3 per rank
    __shared__ float s_ae[RPB][NREF * 3];  // per-row edge constant
    __shared__ float s_ey[NREF * 3];

    const int tid = threadIdx.x;
    const int base = blockIdx.x * RPB;
    const int wid = tid >> 6, lane = tid & 63;

    // preload valid into registers FIRST: latency overlaps the depth staging
    // wait at the first barrier instead of stalling the compute loop.
    int vreg[RPB][10];
    {
        const int* vb = valid + base * WW + lane;
        #pragma unroll
        for (int rr = 0; rr < RPB; rr++)
            #pragma unroll
            for (int j = 0; j < 10; j++)
                vreg[rr][j] = vb[rr * WW + j * 64];
    }

    if (tid < NL) s_sc[tid] = ((const float2*)line_score)[tid].x;

    // stage depth: (RPB+2) rows x 160 float4
    for (int idx = tid; idx < (RPB + 2) * (WW / 4); idx += 256) {
        const int lr = idx / (WW / 4);
        const int c4 = idx - lr * (WW / 4);
        const int g = base - 1 + lr;
        float4 v = make_float4(0.f, 0.f, 0.f, 0.f);
        if ((unsigned)g < (unsigned)HH) v = ((const float4*)depth)[g * (WW / 4) + c4];
        ((float4*)ds)[idx] = v;
    }
    __syncthreads();

    // stable rank == jax.lax.top_k order (desc, ties -> lower idx); permutation
    if (tid < NL) {
        const float s0 = s_sc[tid];
        int rank = 0;
        for (int j = 0; j < NL; j++) {
            const float sj = s_sc[j];
            rank += ((sj > s0) || (sj == s0 && j < tid)) ? 1 : 0;
        }
        if (rank < NREF) {
            const float2 c01 = ((const float2*)line_pred)[3 * tid];
            const float2 c23 = ((const float2*)line_pred)[3 * tid + 1];
            const float2 c45 = ((const float2*)line_pred)[3 * tid + 2];
            // round half-even == jnp.round; clip to image
            s_vert[rank][0] = fminf(fmaxf(rintf(c01.x * (float)WW), 0.f), (float)(WW - 1));
            s_vert[rank][1] = fminf(fmaxf(rintf(c01.y * (float)HH), 0.f), (float)(HH - 1));
            s_vert[rank][2] = fminf(fmaxf(rintf(c23.x * (float)WW), 0.f), (float)(WW - 1));
            s_vert[rank][3] = fminf(fmaxf(rintf(c23.y * (float)HH), 0.f), (float)(HH - 1));
            s_vert[rank][4] = fminf(fmaxf(rintf(c45.x * (float)WW), 0.f), (float)(WW - 1));
            s_vert[rank][5] = fminf(fmaxf(rintf(c45.y * (float)HH), 0.f), (float)(HH - 1));
        }
    }
    __syncthreads();

    // per-row edge constants: d_e(px) = ae_e - ey_e*px (exact: integer fp32
    // operands, |terms| < 2^22 -> sign test bitwise-identical to reference)
    if (tid < NREF * 3) {
        const int t = tid / 3, e = tid - 3 * t, n = (e + 1) % 3;
        const float vx = s_vert[t][2 * e], vy = s_vert[t][2 * e + 1];
        const float ex = s_vert[t][2 * n] - vx, eyv = s_vert[t][2 * n + 1] - vy;
        s_ey[tid] = eyv;
        #pragma unroll
        for (int rr = 0; rr < RPB; rr++)
            s_ae[rr][tid] = fmaf(ex, (float)(base + rr) - vy, eyv * vx);
    }
    __syncthreads();

    float eyr[5][3];
    #pragma unroll
    for (int i = 0; i < 5; i++)
        #pragma unroll
        for (int e = 0; e < 3; e++)
            eyr[i][e] = s_ey[(wid * 5 + i) * 3 + e];

    float acc[5][4];
    #pragma unroll
    for (int i = 0; i < 5; i++)
        #pragma unroll
        for (int q = 0; q < 4; q++) acc[i][q] = 0.f;

    #pragma unroll
    for (int rr = 0; rr < RPB; rr++) {
        float ae[5][3];
        #pragma unroll
        for (int i = 0; i < 5; i++)
            #pragma unroll
            for (int e = 0; e < 3; e++)
                ae[i][e] = s_ae[rr][(wid * 5 + i) * 3 + e];
        const float* rm = ds + rr * WW;
        const float* rc = ds + (rr + 1) * WW;
        const float* rp = ds + (rr + 2) * WW;
        #pragma unroll
        for (int j = 0; j < 10; j++) {
            const int x = j * 64 + lane;
            const float px = (float)x;
            const float fl = (x > 0) ? 1.f : 0.f;
            const float fr = (x < WW - 1) ? 1.f : 0.f;
            const int xm = x - (x > 0), xp = x + (x < WW - 1);
            const float a00 = rm[xm] * fl, a01 = rm[x], a02 = rm[xp] * fr;
            const float a10 = rc[xm] * fl,               a12 = rc[xp] * fr;
            const float a20 = rp[xm] * fl, a21 = rp[x], a22 = rp[xp] * fr;
            // XLA conv = cross-correlation, zero pad
            const float gx = (a00 - a02) + 2.f * (a10 - a12) + (a20 - a22);
            const float gy = (a00 + 2.f * a01 + a02) - (a20 + 2.f * a21 + a22);
            const float nx = -gx, ny = -gy;
            const float s2 = nx * nx + ny * ny;
            const bool vm = (vreg[rr][j] != 0);
            #pragma unroll
            for (int i = 0; i < 5; i++) {
                const float d0 = fmaf(-eyr[i][0], px, ae[i][0]);
                const float d1 = fmaf(-eyr[i][1], px, ae[i][1]);
                const float d2 = fmaf(-eyr[i][2], px, ae[i][2]);
                const float dmin = fminf(fminf(d0, d1), d2);
                const float dmax = fmaxf(fmaxf(d0, d1), d2);
                const bool m = ((dmin >= 0.f) | (dmax <= 0.f)) & vm;
                const float mf = m ? 1.f : 0.f;
                acc[i][0] += mf;
                acc[i][1] = fmaf(mf, nx, acc[i][1]);
                acc[i][2] = fmaf(mf, ny, acc[i][2]);
                acc[i][3] = fmaf(mf, s2, acc[i][3]);
            }
        }
    }

    // wave-level reduction; waves own disjoint triangles -> no cross-wave step
    #pragma unroll
    for (int off = 32; off > 0; off >>= 1)
        #pragma unroll
        for (int i = 0; i < 5; i++)
            #pragma unroll
            for (int q = 0; q < 4; q++)
                acc[i][q] += __shfl_down(acc[i][q], off);
    if (lane == 0) {
        // plain stores, zero contention: col = (wid*5+i)*4+q, row = blockIdx.x
        #pragma unroll
        for (int i = 0; i < 5; i++)
            #pragma unroll
            for (int q = 0; q < 4; q++)
                w[((wid * 5 + i) * 4 + q) * NB + blockIdx.x] = acc[i][q];
    }
}

__global__ __launch_bounds__(128) void plane_finalize_kernel(
    const float* __restrict__ line_score, const float* __restrict__ w,
    float* __restrict__ out) {
    __shared__ float s_col[NREF * 4];
    __shared__ int s_cnt[2];
    const int tid = threadIdx.x; // 0..127
    const int lane = tid & 63, wid = tid >> 6;

    // sum partial columns FIRST so the loads issue before the ballot work.
    // (NB contiguous floats each, float4). unroll 15: 15 independent float4
    // loads in flight -> 4 latency round trips. Accumulation order is the
    // same strictly-sequential per-lane order -> bitwise-identical result.
    if (tid < NREF * 4) {
        const float4* col = (const float4*)(w + tid * NB);
        float4 s4 = make_float4(0.f, 0.f, 0.f, 0.f);
        #pragma unroll 15
        for (int p = 0; p < NB / 4; p++) {
            const float4 v = col[p];
            s4.x += v.x; s4.y += v.y; s4.z += v.z; s4.w += v.w;
        }
        s_col[tid] = (s4.x + s4.y) + (s4.z + s4.w);
    }

    // top_num = min(#(softmax prob0 > 0.6), 20); include-flag = (rank < top_num)
    int flag = 0;
    if (tid < NL) {
        const float2 sc = ((const float2*)line_score)[tid];
        const float p0 = 1.0f / (1.0f + expf(sc.y - sc.x));
        flag = (p0 > 0.6f) ? 1 : 0;
    }
    const unsigned long long b = __ballot(flag);
    if (lane == 0) s_cnt[wid] = __popcll(b);
    __syncthreads();

    const int topnum = min(s_cnt[0] + s_cnt[1], NREF);
    float val = 0.f, inc = 0.f;
    if (tid < NREF) {
        const float c  = s_col[tid * 4 + 0];
        const float sx = s_col[tid * 4 + 1];
        const float sy = s_col[tid * 4 + 2];
        const float sq = s_col[tid * 4 + 3];
        const float safe = fmaxf(c, 1.f);
        const float mx = sx / safe, my = sy / safe;
        // (var_x+var_y) expanded; exact 0 when c==0
        const float var = (sq - 2.f * mx * sx - 2.f * my * sy
                           + c * (mx * mx + my * my)) / safe;
        inc = ((c >= 100.f) && (tid < topnum)) ? 1.f : 0.f;
        val = inc * var;
    }
    if (tid < 64) { // lanes 20..63 carry zeros
        #pragma unroll
        for (int off = 32; off > 0; off >>= 1) {
            val += __shfl_down(val, off);
            inc += __shfl_down(inc, off);
        }
        if (tid == 0) out[0] = val / fmaxf(inc, 1.f);
    }
}

extern "C" void kernel_launch(void* const* d_in, const int* in_sizes, int n_in,
                              void* d_out, int out_size, void* d_ws, size_t ws_size,
                              hipStream_t stream) {
    const float* depth_pred = (const float*)d_in[0];
    // d_in[1] = depth_gt (unused by reference)
    const float* line_pred  = (const float*)d_in[2];
    const float* line_score = (const float*)d_in[3];
    const int*   valid_mask = (const int*)d_in[4];
    float* out = (float*)d_out;
    float* w = (float*)d_ws;

    plane_main_kernel<<<NB, 256, 0, stream>>>(depth_pred, valid_mask,
                                              line_pred, line_score, w);
    plane_finalize_kernel<<<1, 128, 0, stream>>>(line_score, w, out);
}